// Round 10
// baseline (431.279 us; speedup 1.0000x reference)
//
#include <hip/hip_runtime.h>
#include <math.h>

#define NNODES 50000
#define NEDGES 800000
#define NSB 49       // scan blocks: ceil(50000/1024)
#define NPACK 40     // weight-pack tile blocks (64x64 transpose tiles)
#define NCVT 3125    // x->bf16 convert blocks: 50000*256/(256*16)
#define EBH 3125     // hist blocks: 800000/256
#define NBM 391      // gemm row-tile blocks: ceil(50000/128)
#define SCB 1563     // scatter blocks @512: ceil(800000/512)

using ushort8v = __attribute__((ext_vector_type(8))) unsigned short;

__device__ __forceinline__ float leaky(float x) { return x > 0.f ? x : 0.2f * x; }

__device__ __forceinline__ ushort f2bf(float f) {
    unsigned u = __float_as_uint(f);
    return (ushort)((u + 0x7fffu + ((u >> 16) & 1u)) >> 16);  // RNE
}
__device__ __forceinline__ float bf2f(ushort u) {
    return __uint_as_float((unsigned)u << 16);
}

typedef const __attribute__((address_space(1))) void* gptr_t;
typedef __attribute__((address_space(3))) void* lptr_t;

// ---- front: hist | weight pack (LDS tile transpose) | x->bf16 convert ----
__global__ __launch_bounds__(256) void front_kernel(
    const int* __restrict__ dst, int* __restrict__ counts,
    const float* __restrict__ W0, const float* __restrict__ W1, const float* __restrict__ W2,
    const float* __restrict__ Wr, ushort* __restrict__ Bt0, ushort* __restrict__ Bt1,
    ushort* __restrict__ Bt2, const float* __restrict__ x, ushort* __restrict__ xb) {
    __shared__ float tile[64][65];
    int t = threadIdx.x;
    if (blockIdx.x < EBH) {
        int e = blockIdx.x * 256 + t;
        if (e < NEDGES) atomicAdd(&counts[dst[e]], 1);
    } else if (blockIdx.x < EBH + NPACK) {
        int p = blockIdx.x - EBH;
        const float* Wsrc;
        ushort* Bdst;
        int tr, tc, Wcols;
        if (p < 16)      { Wsrc = W0; Bdst = Bt0; tr = p >> 2; tc = p & 3; Wcols = 256; }
        else if (p < 32) { int q = p - 16; Wsrc = W1; Bdst = Bt1; tr = q >> 2; tc = q & 3; Wcols = 256; }
        else if (p < 36) { Wsrc = W2; Bdst = Bt2; tr = p - 32; tc = 0; Wcols = 64; }
        else             { Wsrc = Wr; Bdst = Bt2 + 64 * 256; tr = p - 36; tc = 0; Wcols = 64; }
        // load 64x64 fp32 tile, coalesced
        int rr = t >> 2, cc = (t & 3) * 16;
        const float* srcp = Wsrc + (size_t)(tr * 64 + rr) * Wcols + tc * 64 + cc;
#pragma unroll
        for (int j = 0; j < 4; ++j) {
            float4 v = *reinterpret_cast<const float4*>(srcp + j * 4);
            tile[rr][cc + j * 4 + 0] = v.x;
            tile[rr][cc + j * 4 + 1] = v.y;
            tile[rr][cc + j * 4 + 2] = v.z;
            tile[rr][cc + j * 4 + 3] = v.w;
        }
        __syncthreads();
        // write transposed bf16, coalesced ushort8
        int n = t >> 2, kc2 = (t & 3) * 16;
        union { ushort8v v; ushort u[8]; } o0, o1;
#pragma unroll
        for (int j = 0; j < 8; ++j) o0.u[j] = f2bf(tile[kc2 + j][n]);
#pragma unroll
        for (int j = 0; j < 8; ++j) o1.u[j] = f2bf(tile[kc2 + 8 + j][n]);
        ushort* op = Bdst + (size_t)(tc * 64 + n) * 256 + tr * 64 + kc2;
        *reinterpret_cast<ushort8v*>(op) = o0.v;
        *reinterpret_cast<ushort8v*>(op + 8) = o1.v;
    } else {
        size_t j = (size_t)(blockIdx.x - EBH - NPACK) * 4096 + t * 16;  // 3125*4096 = 12.8M exact
        float4 a0 = *reinterpret_cast<const float4*>(x + j);
        float4 a1 = *reinterpret_cast<const float4*>(x + j + 4);
        float4 a2 = *reinterpret_cast<const float4*>(x + j + 8);
        float4 a3 = *reinterpret_cast<const float4*>(x + j + 12);
        union { ushort8v v; ushort u[8]; } p0, p1;
        p0.u[0] = f2bf(a0.x); p0.u[1] = f2bf(a0.y); p0.u[2] = f2bf(a0.z); p0.u[3] = f2bf(a0.w);
        p0.u[4] = f2bf(a1.x); p0.u[5] = f2bf(a1.y); p0.u[6] = f2bf(a1.z); p0.u[7] = f2bf(a1.w);
        p1.u[0] = f2bf(a2.x); p1.u[1] = f2bf(a2.y); p1.u[2] = f2bf(a2.z); p1.u[3] = f2bf(a2.w);
        p1.u[4] = f2bf(a3.x); p1.u[5] = f2bf(a3.y); p1.u[6] = f2bf(a3.z); p1.u[7] = f2bf(a3.w);
        *reinterpret_cast<ushort8v*>(xb + j) = p0.v;
        *reinterpret_cast<ushort8v*>(xb + j + 8) = p1.v;
    }
}

__global__ __launch_bounds__(256) void scan_partial(const int* __restrict__ counts,
                                                    int* __restrict__ bsum, int Nn) {
    int b = blockIdx.x, t = threadIdx.x;
    int base = b * 1024;
    int v = 0;
#pragma unroll
    for (int i = 0; i < 4; ++i) {
        int idx = base + t + 256 * i;
        if (idx < Nn) v += counts[idx];
    }
    for (int o = 32; o; o >>= 1) v += __shfl_xor(v, o);
    __shared__ int ws[4];
    if ((t & 63) == 0) ws[t >> 6] = v;
    __syncthreads();
    if (t == 0) bsum[b] = ws[0] + ws[1] + ws[2] + ws[3];
}

__global__ __launch_bounds__(256) void scan_final(const int* __restrict__ counts,
                                                  const int* __restrict__ bsum,
                                                  int* __restrict__ row_start, int Nn, int nB) {
    __shared__ int off_s;
    __shared__ int tsum[256];
    int b = blockIdx.x, t = threadIdx.x;
    if (t == 0) {
        int o = 0;
        for (int i = 0; i < b; ++i) o += bsum[i];
        off_s = o;
    }
    int base = b * 1024 + t * 4;
    int c0 = 0, c1 = 0, c2 = 0, c3 = 0;
    if (base + 3 < Nn) {
        int4 c = *reinterpret_cast<const int4*>(counts + base);
        c0 = c.x; c1 = c.y; c2 = c.z; c3 = c.w;
    } else {
        if (base + 0 < Nn) c0 = counts[base + 0];
        if (base + 1 < Nn) c1 = counts[base + 1];
        if (base + 2 < Nn) c2 = counts[base + 2];
        if (base + 3 < Nn) c3 = counts[base + 3];
    }
    int s0 = c0, s1 = s0 + c1, s2 = s1 + c2, s3 = s2 + c3;
    tsum[t] = s3;
    __syncthreads();
    for (int o = 1; o < 256; o <<= 1) {
        int u = (t >= o) ? tsum[t - o] : 0;
        __syncthreads();
        tsum[t] += u;
        __syncthreads();
    }
    int o = off_s + tsum[t] - s3;
    if (base + 3 < Nn) {
        *reinterpret_cast<int4*>(row_start + base) = make_int4(o, o + s0, o + s1, o + s2);
    } else {
        if (base + 0 < Nn) row_start[base + 0] = o;
        if (base + 1 < Nn) row_start[base + 1] = o + s0;
        if (base + 2 < Nn) row_start[base + 2] = o + s1;
        if (base + 3 < Nn) row_start[base + 3] = o + s2;
    }
    if (b == nB - 1 && t == 255) row_start[Nn] = off_s + tsum[255];
}

// ---- 512-thread MFMA GEMM, 128x256 per block; optional fused scatter blocks ----
template <bool SCAT>
__global__ __launch_bounds__(512) void gemm_wide(const ushort* __restrict__ Ab,
                                                 const ushort* __restrict__ Bt,
                                                 const float* __restrict__ al,
                                                 const float* __restrict__ ar,
                                                 ushort* __restrict__ featb,
                                                 float* __restrict__ el, float* __restrict__ er,
                                                 int Nrows,
                                                 const int* __restrict__ srcv,
                                                 const int* __restrict__ dstv,
                                                 const int* __restrict__ row_start,
                                                 int* __restrict__ cursor,
                                                 int* __restrict__ csr_src) {
    using bf16x8 = __attribute__((ext_vector_type(8))) short;
    using f32x4 = __attribute__((ext_vector_type(4))) float;
    __shared__ ushort As[8192];   // 128 rows x 64 k
    __shared__ ushort Bs[16384];  // 256 cols x 64 k; reused as epilogue bounce tile
    if constexpr (SCAT) {
        if (blockIdx.x >= NBM) {
            int e = (blockIdx.x - NBM) * 512 + threadIdx.x;
            if (e < NEDGES) {
                int d = dstv[e];
                int pos = row_start[d] + atomicAdd(&cursor[d], 1);
                csr_src[pos] = srcv[e];
            }
            return;
        }
    }
    const int tid = threadIdx.x;
    const int lane = tid & 63;
    const int wave = tid >> 6;
    const int wr = wave >> 2, wc = wave & 3;
    const int q = lane >> 4, li = lane & 15;
    const int r0 = blockIdx.x * 128;

    f32x4 acc[4][4];
#pragma unroll
    for (int i = 0; i < 4; ++i)
#pragma unroll
        for (int j = 0; j < 4; ++j) acc[i][j] = (f32x4){0.f, 0.f, 0.f, 0.f};

    for (int kk = 0; kk < 256; kk += 64) {
        __syncthreads();
#pragma unroll
        for (int j = 0; j < 2; ++j) {
            int c = wave * 128 + j * 64 + lane;
            int mr = c & 15, kg = (c >> 4) & 7, mf = c >> 7;
            const ushort* gp = Ab + (size_t)(r0 + mf * 16 + mr) * 256 + kk + kg * 8;
            void* lp = (char*)As + (size_t)(wave * 2 + j) * 1024;
            __builtin_amdgcn_global_load_lds((gptr_t)gp, (lptr_t)lp, 16, 0, 0);
        }
#pragma unroll
        for (int j = 0; j < 4; ++j) {
            int c = wave * 256 + j * 64 + lane;
            int nr = c & 15, kg = (c >> 4) & 7, nf = c >> 7;
            const ushort* gp = Bt + (size_t)(nf * 16 + nr) * 256 + kk + kg * 8;
            void* lp = (char*)Bs + (size_t)(wave * 4 + j) * 1024;
            __builtin_amdgcn_global_load_lds((gptr_t)gp, (lptr_t)lp, 16, 0, 0);
        }
        __syncthreads();
#pragma unroll
        for (int t = 0; t < 2; ++t) {
            const int kc = t * 4 + q;
            bf16x8 af[4], bfv[4];
#pragma unroll
            for (int f = 0; f < 4; ++f) {
                af[f] = *reinterpret_cast<const bf16x8*>(
                    &As[(((wr * 4 + f) * 8 + kc) * 16 + li) * 8]);
                bfv[f] = *reinterpret_cast<const bf16x8*>(
                    &Bs[(((wc * 4 + f) * 8 + kc) * 16 + li) * 8]);
            }
#pragma unroll
            for (int f = 0; f < 4; ++f)
#pragma unroll
                for (int f2 = 0; f2 < 4; ++f2)
                    acc[f][f2] =
                        __builtin_amdgcn_mfma_f32_16x16x32_bf16(af[f], bfv[f2], acc[f][f2], 0, 0, 0);
        }
    }

    // ---- el/er (register + shuffle, unchanged math) ----
    float alv[4], arv[4];
#pragma unroll
    for (int f2 = 0; f2 < 4; ++f2) {
        alv[f2] = al[wc * 64 + f2 * 16 + li];
        arv[f2] = ar[wc * 64 + f2 * 16 + li];
    }
#pragma unroll
    for (int f = 0; f < 4; ++f) {
#pragma unroll
        for (int r = 0; r < 4; ++r) {
            int row = r0 + wr * 64 + f * 16 + q * 4 + r;
            bool ok = row < Nrows;
            float elp = 0.f, erp = 0.f;
#pragma unroll
            for (int f2 = 0; f2 < 4; ++f2) {
                float v = acc[f][f2][r];
                elp = fmaf(v, alv[f2], elp);
                erp = fmaf(v, arv[f2], erp);
            }
#pragma unroll
            for (int o = 1; o < 16; o <<= 1) {
                elp += __shfl_xor(elp, o);
                erp += __shfl_xor(erp, o);
            }
            if (ok && li == 0) {
                el[row * 4 + wc] = elp;
                er[row * 4 + wc] = erp;
            }
        }
    }

    // ---- featb via LDS bounce: write in final [n][d][h] order, flush coalesced ----
    ushort* T = Bs;  // 32 rows x 256 ushorts = 16KB <= Bs
#pragma unroll
    for (int f = 0; f < 4; ++f) {
        __syncthreads();  // waves done reading Bs (f=0) / done flushing (f>0)
#pragma unroll
        for (int r = 0; r < 4; ++r)
#pragma unroll
            for (int f2 = 0; f2 < 4; ++f2)
                T[(wr * 16 + q * 4 + r) * 256 + (f2 * 16 + li) * 4 + wc] = f2bf(acc[f][f2][r]);
        __syncthreads();
#pragma unroll
        for (int it = 0; it < 2; ++it) {
            int tt = it * 512 + tid;   // 0..1023
            int lr = tt >> 5;          // 0..31
            int o16 = tt & 31;         // 16B chunk in row
            int grow = r0 + (lr >> 4) * 64 + f * 16 + (lr & 15);
            if (grow < Nrows) {
                ushort8v v = *reinterpret_cast<const ushort8v*>(&T[lr * 256 + o16 * 8]);
                *reinterpret_cast<ushort8v*>(&featb[(size_t)grow * 256 + o16 * 8]) = v;
            }
        }
    }
}

// ---- layer-2 GEMM: 256 threads, 128x128 (featb/resid stores already coalesced) ----
__global__ __launch_bounds__(256) void gemm_l2(const ushort* __restrict__ Ab,
                                               const ushort* __restrict__ Bt,
                                               const float* __restrict__ al,
                                               const float* __restrict__ ar,
                                               ushort* __restrict__ featb,
                                               float* __restrict__ el, float* __restrict__ er,
                                               float* __restrict__ resid, int Nrows) {
    using bf16x8 = __attribute__((ext_vector_type(8))) short;
    using f32x4 = __attribute__((ext_vector_type(4))) float;
    __shared__ ushort As[8192];
    __shared__ ushort Bs[8192];
    const int tid = threadIdx.x;
    const int lane = tid & 63;
    const int wave = tid >> 6;
    const int wr = wave >> 1, wc = wave & 1;
    const int q = lane >> 4, li = lane & 15;
    const int r0 = blockIdx.x * 128;

    f32x4 acc[4][4];
#pragma unroll
    for (int i = 0; i < 4; ++i)
#pragma unroll
        for (int j = 0; j < 4; ++j) acc[i][j] = (f32x4){0.f, 0.f, 0.f, 0.f};

    for (int kk = 0; kk < 256; kk += 64) {
        __syncthreads();
#pragma unroll
        for (int j = 0; j < 4; ++j) {
            int c = (wave * 4 + j) * 64 + lane;
            int mr = c & 15, kg = (c >> 4) & 7, mf = c >> 7;
            const ushort* gp = Ab + (size_t)(r0 + mf * 16 + mr) * 256 + kk + kg * 8;
            void* lp = (char*)As + (size_t)(wave * 4 + j) * 1024;
            __builtin_amdgcn_global_load_lds((gptr_t)gp, (lptr_t)lp, 16, 0, 0);
        }
#pragma unroll
        for (int j = 0; j < 4; ++j) {
            int c = (wave * 4 + j) * 64 + lane;
            int nr = c & 15, kg = (c >> 4) & 7, nf = c >> 7;
            const ushort* gp = Bt + (size_t)(nf * 16 + nr) * 256 + kk + kg * 8;
            void* lp = (char*)Bs + (size_t)(wave * 4 + j) * 1024;
            __builtin_amdgcn_global_load_lds((gptr_t)gp, (lptr_t)lp, 16, 0, 0);
        }
        __syncthreads();
#pragma unroll
        for (int t = 0; t < 2; ++t) {
            const int kc = t * 4 + q;
            bf16x8 af[4], bfv[4];
#pragma unroll
            for (int f = 0; f < 4; ++f) {
                af[f] = *reinterpret_cast<const bf16x8*>(
                    &As[(((wr * 4 + f) * 8 + kc) * 16 + li) * 8]);
                bfv[f] = *reinterpret_cast<const bf16x8*>(
                    &Bs[(((wc * 4 + f) * 8 + kc) * 16 + li) * 8]);
            }
#pragma unroll
            for (int f = 0; f < 4; ++f)
#pragma unroll
                for (int f2 = 0; f2 < 4; ++f2)
                    acc[f][f2] =
                        __builtin_amdgcn_mfma_f32_16x16x32_bf16(af[f], bfv[f2], acc[f][f2], 0, 0, 0);
        }
    }

    if (wc == 0) {
        float alv[4], arv[4];
#pragma unroll
        for (int f2 = 0; f2 < 4; ++f2) {
            alv[f2] = al[f2 * 16 + li];
            arv[f2] = ar[f2 * 16 + li];
        }
#pragma unroll
        for (int f = 0; f < 4; ++f) {
#pragma unroll
            for (int r = 0; r < 4; ++r) {
                int row = r0 + wr * 64 + f * 16 + q * 4 + r;
                bool ok = row < Nrows;
                float elp = 0.f, erp = 0.f;
#pragma unroll
                for (int f2 = 0; f2 < 4; ++f2) {
                    float v = acc[f][f2][r];
                    elp = fmaf(v, alv[f2], elp);
                    erp = fmaf(v, arv[f2], erp);
                    if (ok) featb[(size_t)row * 64 + f2 * 16 + li] = f2bf(v);
                }
#pragma unroll
                for (int o = 1; o < 16; o <<= 1) {
                    elp += __shfl_xor(elp, o);
                    erp += __shfl_xor(erp, o);
                }
                if (ok && li == 0) {
                    el[row] = elp;
                    er[row] = erp;
                }
            }
        }
    } else {
#pragma unroll
        for (int f = 0; f < 4; ++f) {
#pragma unroll
            for (int r = 0; r < 4; ++r) {
                int row = r0 + wr * 64 + f * 16 + q * 4 + r;
                if (row < Nrows) {
#pragma unroll
                    for (int f2 = 0; f2 < 4; ++f2)
                        resid[(size_t)row * 64 + f2 * 16 + li] = acc[f][f2][r];
                }
            }
        }
    }
}

// ---------------- agg H=4: 2 edges/iter, 32 lanes x ushort8 (16B) each ----------------
template <int RES, bool ACT>
__global__ __launch_bounds__(256) void agg4_kernel(
    const ushort* __restrict__ featb, const float* __restrict__ el,
    const float* __restrict__ er, const int* __restrict__ row_start,
    const int* __restrict__ csr_src, const ushort* __restrict__ resbuf,
    const float* __restrict__ bias, ushort* __restrict__ out, int Nn) {
    __shared__ float wbuf[4][256];
    __shared__ int obuf[4][64];
    const int wv = threadIdx.x >> 6, lane = threadIdx.x & 63;
    const int g = lane >> 5, li = lane & 31;
    int node = blockIdx.x * 4 + wv;
    if (node >= Nn) return;

    int begin = row_start[node], end = row_start[node + 1];
    float4 ern = *(reinterpret_cast<const float4*>(er) + node);

    float denom[4] = {0.f, 0.f, 0.f, 0.f};
    float acc[2][4] = {{0.f, 0.f, 0.f, 0.f}, {0.f, 0.f, 0.f, 0.f}};

    for (int c = begin; c < end; c += 64) {
        int nE = min(64, end - c);
        float4 w = make_float4(0.f, 0.f, 0.f, 0.f);
        int s = 0;
        if (lane < nE) {
            s = csr_src[c + lane];
            float4 e4 = *(reinterpret_cast<const float4*>(el) + s);
            w.x = __expf(leaky(e4.x + ern.x));
            w.y = __expf(leaky(e4.y + ern.y));
            w.z = __expf(leaky(e4.z + ern.z));
            w.w = __expf(leaky(e4.w + ern.w));
        }
        denom[0] += w.x; denom[1] += w.y; denom[2] += w.z; denom[3] += w.w;
        obuf[wv][lane] = s * 256;
        *reinterpret_cast<float4*>(&wbuf[wv][lane * 4]) = w;
        __asm__ volatile("s_waitcnt lgkmcnt(0)" ::: "memory");

#pragma unroll 4
        for (int e2 = 0; e2 < nE; e2 += 2) {
            int e = e2 + g;
            float4 we = make_float4(0.f, 0.f, 0.f, 0.f);
            int off = 0;
            if (e < nE) {
                off = obuf[wv][e];
                we = *reinterpret_cast<const float4*>(&wbuf[wv][e * 4]);
            }
            ushort8v v = *reinterpret_cast<const ushort8v*>(featb + off + li * 8);
            acc[0][0] = fmaf(we.x, bf2f(v[0]), acc[0][0]);
            acc[0][1] = fmaf(we.y, bf2f(v[1]), acc[0][1]);
            acc[0][2] = fmaf(we.z, bf2f(v[2]), acc[0][2]);
            acc[0][3] = fmaf(we.w, bf2f(v[3]), acc[0][3]);
            acc[1][0] = fmaf(we.x, bf2f(v[4]), acc[1][0]);
            acc[1][1] = fmaf(we.y, bf2f(v[5]), acc[1][1]);
            acc[1][2] = fmaf(we.z, bf2f(v[6]), acc[1][2]);
            acc[1][3] = fmaf(we.w, bf2f(v[7]), acc[1][3]);
        }
        __asm__ volatile("" ::: "memory");
    }

#pragma unroll
    for (int j = 0; j < 2; ++j)
#pragma unroll
        for (int h = 0; h < 4; ++h) acc[j][h] += __shfl_xor(acc[j][h], 32);
#pragma unroll
    for (int h = 0; h < 4; ++h)
        for (int o = 32; o; o >>= 1) denom[h] += __shfl_xor(denom[h], o);

    bool has = end > begin;
#pragma unroll
    for (int hh = 0; hh < 2; ++hh) {
        int h = g * 2 + hh;
        float d0 = denom[h];
        float o0 = has ? acc[0][h] / d0 : 0.f;
        float o1 = has ? acc[1][h] / d0 : 0.f;
        int dbase = h * 64 + li * 2;
        if constexpr (RES == 1) {
            unsigned rv = *reinterpret_cast<const unsigned*>(resbuf + (size_t)node * 256 + dbase);
            o0 += bf2f((ushort)(rv & 0xffffu));
            o1 += bf2f((ushort)(rv >> 16));
        }
        float2 bv = *reinterpret_cast<const float2*>(bias + dbase);
        o0 += bv.x; o1 += bv.y;
        if constexpr (ACT) {
            o0 = o0 > 0.f ? o0 : __expf(o0) - 1.f;
            o1 = o1 > 0.f ? o1 : __expf(o1) - 1.f;
        }
        unsigned pk = (unsigned)f2bf(o0) | ((unsigned)f2bf(o1) << 16);
        *reinterpret_cast<unsigned*>(out + (size_t)node * 256 + dbase) = pk;
    }
}

// ---------------- agg H=1 (layer 2) ----------------
__global__ __launch_bounds__(256) void agg1_kernel(
    const ushort* __restrict__ featb, const float* __restrict__ el,
    const float* __restrict__ er, const int* __restrict__ row_start,
    const int* __restrict__ csr_src, const float* __restrict__ resbuf,
    const float* __restrict__ bias, float* __restrict__ out, int Nn) {
    __shared__ float wbuf[4][64];
    __shared__ int obuf[4][64];
    const int wv = threadIdx.x >> 6, lane = threadIdx.x & 63;
    const int g = lane >> 4, li = lane & 15;
    int node = blockIdx.x * 4 + wv;
    if (node >= Nn) return;

    int begin = row_start[node], end = row_start[node + 1];
    float ern = er[node];
    float denom = 0.f;
    float acc[4] = {0.f, 0.f, 0.f, 0.f};

    for (int c = begin; c < end; c += 64) {
        int nE = min(64, end - c);
        float w = 0.f;
        int s = 0;
        if (lane < nE) {
            s = csr_src[c + lane];
            w = __expf(leaky(el[s] + ern));
        }
        denom += w;
        obuf[wv][lane] = s * 64;
        wbuf[wv][lane] = w;
        __asm__ volatile("s_waitcnt lgkmcnt(0)" ::: "memory");

#pragma unroll 2
        for (int e4i = 0; e4i < nE; e4i += 4) {
            int e = e4i + g;
            float we = 0.f;
            int off = 0;
            if (e < nE) {
                off = obuf[wv][e];
                we = wbuf[wv][e];
            }
            ushort4 v = *reinterpret_cast<const ushort4*>(featb + off + li * 4);
            acc[0] = fmaf(we, bf2f(v.x), acc[0]);
            acc[1] = fmaf(we, bf2f(v.y), acc[1]);
            acc[2] = fmaf(we, bf2f(v.z), acc[2]);
            acc[3] = fmaf(we, bf2f(v.w), acc[3]);
        }
        __asm__ volatile("" ::: "memory");
    }

#pragma unroll
    for (int j = 0; j < 4; ++j) {
        acc[j] += __shfl_xor(acc[j], 16);
        acc[j] += __shfl_xor(acc[j], 32);
    }
    for (int o = 32; o; o >>= 1) denom += __shfl_xor(denom, o);

    if (g == 0) {
        bool has = end > begin;
        float4 rv = *reinterpret_cast<const float4*>(resbuf + (size_t)node * 64 + li * 4);
        float4 bv = *reinterpret_cast<const float4*>(bias + li * 4);
        float4 o4;
        o4.x = (has ? acc[0] / denom : 0.f) + rv.x + bv.x;
        o4.y = (has ? acc[1] / denom : 0.f) + rv.y + bv.y;
        o4.z = (has ? acc[2] / denom : 0.f) + rv.z + bv.z;
        o4.w = (has ? acc[3] / denom : 0.f) + rv.w + bv.w;
        *reinterpret_cast<float4*>(out + (size_t)node * 64 + li * 4) = o4;
    }
}

// ---------------- launch ----------------
extern "C" void kernel_launch(void* const* d_in, const int* in_sizes, int n_in, void* d_out,
                              int out_size, void* d_ws, size_t ws_size, hipStream_t stream) {
    const float* x   = (const float*)d_in[0];
    const int* src   = (const int*)d_in[1];
    const int* dst   = (const int*)d_in[2];
    const float* W0  = (const float*)d_in[3];
    const float* al0 = (const float*)d_in[4];
    const float* ar0 = (const float*)d_in[5];
    const float* b0  = (const float*)d_in[6];
    const float* W1  = (const float*)d_in[7];
    const float* al1 = (const float*)d_in[8];
    const float* ar1 = (const float*)d_in[9];
    const float* b1  = (const float*)d_in[10];
    const float* W2  = (const float*)d_in[11];
    const float* al2 = (const float*)d_in[12];
    const float* ar2 = (const float*)d_in[13];
    const float* b2  = (const float*)d_in[14];
    const float* Wr2 = (const float*)d_in[15];
    float* out = (float*)d_out;

    char* w = (char*)d_ws;
    size_t off = 0;
    auto alloc = [&](size_t bytes) -> char* {
        char* p = w + off;
        off += (bytes + 255) & ~(size_t)255;
        return p;
    };
    ushort* xb      = (ushort*)alloc((size_t)NNODES * 256 * 2);
    ushort* hbuf    = (ushort*)alloc((size_t)NNODES * 256 * 2);
    ushort* featb   = (ushort*)alloc((size_t)NNODES * 256 * 2);
    float* resid    = (float*)alloc((size_t)NNODES * 64 * 4);
    float* el       = (float*)alloc((size_t)NNODES * 4 * 4);
    float* er       = (float*)alloc((size_t)NNODES * 4 * 4);
    ushort* Bt0     = (ushort*)alloc(65536 * 2);
    ushort* Bt1     = (ushort*)alloc(65536 * 2);
    ushort* Bt2     = (ushort*)alloc(32768 * 2);
    int* counts     = (int*)alloc((size_t)NNODES * 4 * 2);
    int* cursor     = counts + NNODES;
    int* row_start  = (int*)alloc((size_t)(NNODES + 1) * 4);
    int* bsum       = (int*)alloc(64 * 4);
    int* csr_src    = (int*)alloc((size_t)NEDGES * 4);

    hipMemsetAsync(counts, 0, (size_t)NNODES * 4 * 2, stream);

    const int NB4 = (NNODES + 3) / 4;

    front_kernel<<<EBH + NPACK + NCVT, 256, 0, stream>>>(dst, counts, W0, W1, W2, Wr2,
                                                         Bt0, Bt1, Bt2, x, xb);
    scan_partial<<<NSB, 256, 0, stream>>>(counts, bsum, NNODES);
    scan_final<<<NSB, 256, 0, stream>>>(counts, bsum, row_start, NNODES, NSB);

    // layer 0 GEMM + scatter fused
    gemm_wide<true><<<NBM + SCB, 512, 0, stream>>>(xb, Bt0, al0, ar0, featb, el, er, NNODES,
                                                   src, dst, row_start, cursor, csr_src);
    agg4_kernel<0, true><<<NB4, 256, 0, stream>>>(featb, el, er, row_start, csr_src,
                                                  nullptr, b0, hbuf, NNODES);
    // layer 1
    gemm_wide<false><<<NBM, 512, 0, stream>>>(hbuf, Bt1, al1, ar1, featb, el, er, NNODES,
                                              nullptr, nullptr, nullptr, nullptr, nullptr);
    agg4_kernel<1, true><<<NB4, 256, 0, stream>>>(featb, el, er, row_start, csr_src,
                                                  hbuf, b1, hbuf, NNODES);
    // layer 2
    gemm_l2<<<NBM, 256, 0, stream>>>(hbuf, Bt2, al2, ar2, featb, el, er, resid, NNODES);
    agg1_kernel<<<NB4, 256, 0, stream>>>(featb, el, er, row_start, csr_src,
                                         resid, b2, out, NNODES);
}

// Round 11
// 419.471 us; speedup vs baseline: 1.0282x; 1.0282x over previous
//
#include <hip/hip_runtime.h>
#include <math.h>

#define NNODES 50000
#define NEDGES 800000
#define NSB 49       // scan blocks: ceil(50000/1024)
#define NPACK 640    // weight-pack blocks
#define NCVT 3125    // x->bf16 convert blocks: 50000*256/(256*16)
#define EBH 3125     // hist blocks: 800000/256
#define NBM 391      // gemm row-tile blocks: ceil(50000/128)
#define SCB 1563     // scatter blocks @512: ceil(800000/512)

__device__ __forceinline__ float leaky(float x) { return x > 0.f ? x : 0.2f * x; }

__device__ __forceinline__ ushort f2bf(float f) {
    unsigned u = __float_as_uint(f);
    return (ushort)((u + 0x7fffu + ((u >> 16) & 1u)) >> 16);  // RNE
}
__device__ __forceinline__ float bf2f(ushort u) {
    return __uint_as_float((unsigned)u << 16);
}

typedef const __attribute__((address_space(1))) void* gptr_t;
typedef __attribute__((address_space(3))) void* lptr_t;

// ---- front: hist | weight pack | x->bf16 convert (independent work, one dispatch) ----
__global__ __launch_bounds__(256) void front_kernel(
    const int* __restrict__ dst, int* __restrict__ counts,
    const float* __restrict__ W0, const float* __restrict__ W1, const float* __restrict__ W2,
    const float* __restrict__ Wr, ushort* __restrict__ Bt0, ushort* __restrict__ Bt1,
    ushort* __restrict__ Bt2, const float* __restrict__ x, ushort* __restrict__ xb) {
    using ushort8v = __attribute__((ext_vector_type(8))) unsigned short;
    int t = threadIdx.x;
    if (blockIdx.x < EBH) {
        int e = blockIdx.x * 256 + t;
        if (e < NEDGES) atomicAdd(&counts[dst[e]], 1);
    } else if (blockIdx.x < EBH + NPACK) {
        int idx = (blockIdx.x - EBH) * 256 + t;  // 0..163839
        if (idx < 65536) {
            int n = idx >> 8, k = idx & 255;
            Bt0[idx] = f2bf(W0[k * 256 + n]);
        } else if (idx < 131072) {
            int j = idx - 65536;
            int n = j >> 8, k = j & 255;
            Bt1[j] = f2bf(W1[k * 256 + n]);
        } else {
            int j = idx - 131072;
            int n = j >> 8, k = j & 255;
            Bt2[j] = f2bf(n < 64 ? W2[k * 64 + n] : Wr[k * 64 + (n - 64)]);
        }
    } else {
        size_t j = (size_t)(blockIdx.x - EBH - NPACK) * 4096 + t * 16;  // 3125*4096 = 12.8M exact
        float4 a0 = *reinterpret_cast<const float4*>(x + j);
        float4 a1 = *reinterpret_cast<const float4*>(x + j + 4);
        float4 a2 = *reinterpret_cast<const float4*>(x + j + 8);
        float4 a3 = *reinterpret_cast<const float4*>(x + j + 12);
        union { ushort8v v; ushort u[8]; } p0, p1;
        p0.u[0] = f2bf(a0.x); p0.u[1] = f2bf(a0.y); p0.u[2] = f2bf(a0.z); p0.u[3] = f2bf(a0.w);
        p0.u[4] = f2bf(a1.x); p0.u[5] = f2bf(a1.y); p0.u[6] = f2bf(a1.z); p0.u[7] = f2bf(a1.w);
        p1.u[0] = f2bf(a2.x); p1.u[1] = f2bf(a2.y); p1.u[2] = f2bf(a2.z); p1.u[3] = f2bf(a2.w);
        p1.u[4] = f2bf(a3.x); p1.u[5] = f2bf(a3.y); p1.u[6] = f2bf(a3.z); p1.u[7] = f2bf(a3.w);
        *reinterpret_cast<ushort8v*>(xb + j) = p0.v;
        *reinterpret_cast<ushort8v*>(xb + j + 8) = p1.v;
    }
}

__global__ __launch_bounds__(256) void scan_partial(const int* __restrict__ counts,
                                                    int* __restrict__ bsum, int Nn) {
    int b = blockIdx.x, t = threadIdx.x;
    int base = b * 1024;
    int v = 0;
#pragma unroll
    for (int i = 0; i < 4; ++i) {
        int idx = base + t + 256 * i;
        if (idx < Nn) v += counts[idx];
    }
    for (int o = 32; o; o >>= 1) v += __shfl_xor(v, o);
    __shared__ int ws[4];
    if ((t & 63) == 0) ws[t >> 6] = v;
    __syncthreads();
    if (t == 0) bsum[b] = ws[0] + ws[1] + ws[2] + ws[3];
}

__global__ __launch_bounds__(256) void scan_final(const int* __restrict__ counts,
                                                  const int* __restrict__ bsum,
                                                  int* __restrict__ row_start, int Nn, int nB) {
    __shared__ int off_s;
    __shared__ int tsum[256];
    int b = blockIdx.x, t = threadIdx.x;
    if (t == 0) {
        int o = 0;
        for (int i = 0; i < b; ++i) o += bsum[i];
        off_s = o;
    }
    int base = b * 1024 + t * 4;
    int c0 = 0, c1 = 0, c2 = 0, c3 = 0;
    if (base + 3 < Nn) {
        int4 c = *reinterpret_cast<const int4*>(counts + base);
        c0 = c.x; c1 = c.y; c2 = c.z; c3 = c.w;
    } else {
        if (base + 0 < Nn) c0 = counts[base + 0];
        if (base + 1 < Nn) c1 = counts[base + 1];
        if (base + 2 < Nn) c2 = counts[base + 2];
        if (base + 3 < Nn) c3 = counts[base + 3];
    }
    int s0 = c0, s1 = s0 + c1, s2 = s1 + c2, s3 = s2 + c3;
    tsum[t] = s3;
    __syncthreads();
    for (int o = 1; o < 256; o <<= 1) {
        int u = (t >= o) ? tsum[t - o] : 0;
        __syncthreads();
        tsum[t] += u;
        __syncthreads();
    }
    int o = off_s + tsum[t] - s3;
    if (base + 3 < Nn) {
        *reinterpret_cast<int4*>(row_start + base) = make_int4(o, o + s0, o + s1, o + s2);
    } else {
        if (base + 0 < Nn) row_start[base + 0] = o;
        if (base + 1 < Nn) row_start[base + 1] = o + s0;
        if (base + 2 < Nn) row_start[base + 2] = o + s1;
        if (base + 3 < Nn) row_start[base + 3] = o + s2;
    }
    if (b == nB - 1 && t == 255) row_start[Nn] = off_s + tsum[255];
}

// ---- 512-thread MFMA GEMM, 128x256 per block; optional fused scatter blocks ----
// SCAT=true: blocks [0,NBM) do GEMM, [NBM, NBM+SCB) do CSR scatter (overlapped).
template <bool SCAT>
__global__ __launch_bounds__(512) void gemm_wide(const ushort* __restrict__ Ab,
                                                 const ushort* __restrict__ Bt,
                                                 const float* __restrict__ al,
                                                 const float* __restrict__ ar,
                                                 ushort* __restrict__ featb,
                                                 float* __restrict__ el, float* __restrict__ er,
                                                 int Nrows,
                                                 const int* __restrict__ srcv,
                                                 const int* __restrict__ dstv,
                                                 const int* __restrict__ row_start,
                                                 int* __restrict__ cursor,
                                                 int* __restrict__ csr_src) {
    using bf16x8 = __attribute__((ext_vector_type(8))) short;
    using f32x4 = __attribute__((ext_vector_type(4))) float;
    __shared__ ushort As[8192];   // 128 rows x 64 k
    __shared__ ushort Bs[16384];  // 256 cols x 64 k
    if constexpr (SCAT) {
        if (blockIdx.x >= NBM) {
            int e = (blockIdx.x - NBM) * 512 + threadIdx.x;
            if (e < NEDGES) {
                int d = dstv[e];
                int pos = row_start[d] + atomicAdd(&cursor[d], 1);
                csr_src[pos] = srcv[e];
            }
            return;
        }
    }
    const int tid = threadIdx.x;
    const int lane = tid & 63;
    const int wave = tid >> 6;
    const int wr = wave >> 2, wc = wave & 3;
    const int q = lane >> 4, li = lane & 15;
    const int r0 = blockIdx.x * 128;

    f32x4 acc[4][4];
#pragma unroll
    for (int i = 0; i < 4; ++i)
#pragma unroll
        for (int j = 0; j < 4; ++j) acc[i][j] = (f32x4){0.f, 0.f, 0.f, 0.f};

    for (int kk = 0; kk < 256; kk += 64) {
        __syncthreads();
#pragma unroll
        for (int j = 0; j < 2; ++j) {
            int c = wave * 128 + j * 64 + lane;
            int mr = c & 15, kg = (c >> 4) & 7, mf = c >> 7;
            const ushort* gp = Ab + (size_t)(r0 + mf * 16 + mr) * 256 + kk + kg * 8;
            void* lp = (char*)As + (size_t)(wave * 2 + j) * 1024;
            __builtin_amdgcn_global_load_lds((gptr_t)gp, (lptr_t)lp, 16, 0, 0);
        }
#pragma unroll
        for (int j = 0; j < 4; ++j) {
            int c = wave * 256 + j * 64 + lane;
            int nr = c & 15, kg = (c >> 4) & 7, nf = c >> 7;
            const ushort* gp = Bt + (size_t)(nf * 16 + nr) * 256 + kk + kg * 8;
            void* lp = (char*)Bs + (size_t)(wave * 4 + j) * 1024;
            __builtin_amdgcn_global_load_lds((gptr_t)gp, (lptr_t)lp, 16, 0, 0);
        }
        __syncthreads();
#pragma unroll
        for (int t = 0; t < 2; ++t) {
            const int kc = t * 4 + q;
            bf16x8 af[4], bfv[4];
#pragma unroll
            for (int f = 0; f < 4; ++f) {
                af[f] = *reinterpret_cast<const bf16x8*>(
                    &As[(((wr * 4 + f) * 8 + kc) * 16 + li) * 8]);
                bfv[f] = *reinterpret_cast<const bf16x8*>(
                    &Bs[(((wc * 4 + f) * 8 + kc) * 16 + li) * 8]);
            }
#pragma unroll
            for (int f = 0; f < 4; ++f)
#pragma unroll
                for (int f2 = 0; f2 < 4; ++f2)
                    acc[f][f2] =
                        __builtin_amdgcn_mfma_f32_16x16x32_bf16(af[f], bfv[f2], acc[f][f2], 0, 0, 0);
        }
    }

    float alv[4], arv[4];
#pragma unroll
    for (int f2 = 0; f2 < 4; ++f2) {
        alv[f2] = al[wc * 64 + f2 * 16 + li];
        arv[f2] = ar[wc * 64 + f2 * 16 + li];
    }
#pragma unroll
    for (int f = 0; f < 4; ++f) {
#pragma unroll
        for (int r = 0; r < 4; ++r) {
            int row = r0 + wr * 64 + f * 16 + q * 4 + r;
            bool ok = row < Nrows;
            float elp = 0.f, erp = 0.f;
#pragma unroll
            for (int f2 = 0; f2 < 4; ++f2) {
                float v = acc[f][f2][r];
                elp = fmaf(v, alv[f2], elp);
                erp = fmaf(v, arv[f2], erp);
                if (ok) featb[(size_t)row * 256 + (f2 * 16 + li) * 4 + wc] = f2bf(v);
            }
#pragma unroll
            for (int o = 1; o < 16; o <<= 1) {
                elp += __shfl_xor(elp, o);
                erp += __shfl_xor(erp, o);
            }
            if (ok && li == 0) {
                el[row * 4 + wc] = elp;
                er[row * 4 + wc] = erp;
            }
        }
    }
}

// ---- layer-2 GEMM: 256 threads, 128x128 ----
__global__ __launch_bounds__(256) void gemm_l2(const ushort* __restrict__ Ab,
                                               const ushort* __restrict__ Bt,
                                               const float* __restrict__ al,
                                               const float* __restrict__ ar,
                                               ushort* __restrict__ featb,
                                               float* __restrict__ el, float* __restrict__ er,
                                               float* __restrict__ resid, int Nrows) {
    using bf16x8 = __attribute__((ext_vector_type(8))) short;
    using f32x4 = __attribute__((ext_vector_type(4))) float;
    __shared__ ushort As[8192];
    __shared__ ushort Bs[8192];
    const int tid = threadIdx.x;
    const int lane = tid & 63;
    const int wave = tid >> 6;
    const int wr = wave >> 1, wc = wave & 1;
    const int q = lane >> 4, li = lane & 15;
    const int r0 = blockIdx.x * 128;

    f32x4 acc[4][4];
#pragma unroll
    for (int i = 0; i < 4; ++i)
#pragma unroll
        for (int j = 0; j < 4; ++j) acc[i][j] = (f32x4){0.f, 0.f, 0.f, 0.f};

    for (int kk = 0; kk < 256; kk += 64) {
        __syncthreads();
#pragma unroll
        for (int j = 0; j < 4; ++j) {
            int c = (wave * 4 + j) * 64 + lane;
            int mr = c & 15, kg = (c >> 4) & 7, mf = c >> 7;
            const ushort* gp = Ab + (size_t)(r0 + mf * 16 + mr) * 256 + kk + kg * 8;
            void* lp = (char*)As + (size_t)(wave * 4 + j) * 1024;
            __builtin_amdgcn_global_load_lds((gptr_t)gp, (lptr_t)lp, 16, 0, 0);
        }
#pragma unroll
        for (int j = 0; j < 4; ++j) {
            int c = (wave * 4 + j) * 64 + lane;
            int nr = c & 15, kg = (c >> 4) & 7, nf = c >> 7;
            const ushort* gp = Bt + (size_t)(nf * 16 + nr) * 256 + kk + kg * 8;
            void* lp = (char*)Bs + (size_t)(wave * 4 + j) * 1024;
            __builtin_amdgcn_global_load_lds((gptr_t)gp, (lptr_t)lp, 16, 0, 0);
        }
        __syncthreads();
#pragma unroll
        for (int t = 0; t < 2; ++t) {
            const int kc = t * 4 + q;
            bf16x8 af[4], bfv[4];
#pragma unroll
            for (int f = 0; f < 4; ++f) {
                af[f] = *reinterpret_cast<const bf16x8*>(
                    &As[(((wr * 4 + f) * 8 + kc) * 16 + li) * 8]);
                bfv[f] = *reinterpret_cast<const bf16x8*>(
                    &Bs[(((wc * 4 + f) * 8 + kc) * 16 + li) * 8]);
            }
#pragma unroll
            for (int f = 0; f < 4; ++f)
#pragma unroll
                for (int f2 = 0; f2 < 4; ++f2)
                    acc[f][f2] =
                        __builtin_amdgcn_mfma_f32_16x16x32_bf16(af[f], bfv[f2], acc[f][f2], 0, 0, 0);
        }
    }

    if (wc == 0) {
        float alv[4], arv[4];
#pragma unroll
        for (int f2 = 0; f2 < 4; ++f2) {
            alv[f2] = al[f2 * 16 + li];
            arv[f2] = ar[f2 * 16 + li];
        }
#pragma unroll
        for (int f = 0; f < 4; ++f) {
#pragma unroll
            for (int r = 0; r < 4; ++r) {
                int row = r0 + wr * 64 + f * 16 + q * 4 + r;
                bool ok = row < Nrows;
                float elp = 0.f, erp = 0.f;
#pragma unroll
                for (int f2 = 0; f2 < 4; ++f2) {
                    float v = acc[f][f2][r];
                    elp = fmaf(v, alv[f2], elp);
                    erp = fmaf(v, arv[f2], erp);
                    if (ok) featb[(size_t)row * 64 + f2 * 16 + li] = f2bf(v);
                }
#pragma unroll
                for (int o = 1; o < 16; o <<= 1) {
                    elp += __shfl_xor(elp, o);
                    erp += __shfl_xor(erp, o);
                }
                if (ok && li == 0) {
                    el[row] = elp;
                    er[row] = erp;
                }
            }
        }
    } else {
#pragma unroll
        for (int f = 0; f < 4; ++f) {
#pragma unroll
            for (int r = 0; r < 4; ++r) {
                int row = r0 + wr * 64 + f * 16 + q * 4 + r;
                if (row < Nrows) {
#pragma unroll
                    for (int f2 = 0; f2 < 4; ++f2)
                        resid[(size_t)row * 64 + f2 * 16 + li] = acc[f][f2][r];
                }
            }
        }
    }
}

// ---------------- agg H=4: 2 edges/iter, 32 lanes x ushort8 (16B) each ----------------
template <int RES, bool ACT>
__global__ __launch_bounds__(256) void agg4_kernel(
    const ushort* __restrict__ featb, const float* __restrict__ el,
    const float* __restrict__ er, const int* __restrict__ row_start,
    const int* __restrict__ csr_src, const ushort* __restrict__ resbuf,
    const float* __restrict__ bias, ushort* __restrict__ out, int Nn) {
    using ushort8v = __attribute__((ext_vector_type(8))) unsigned short;
    __shared__ float wbuf[4][256];
    __shared__ int obuf[4][64];
    const int wv = threadIdx.x >> 6, lane = threadIdx.x & 63;
    const int g = lane >> 5, li = lane & 31;
    int node = blockIdx.x * 4 + wv;
    if (node >= Nn) return;

    int begin = row_start[node], end = row_start[node + 1];
    float4 ern = *(reinterpret_cast<const float4*>(er) + node);

    float denom[4] = {0.f, 0.f, 0.f, 0.f};
    float acc[2][4] = {{0.f, 0.f, 0.f, 0.f}, {0.f, 0.f, 0.f, 0.f}};

    for (int c = begin; c < end; c += 64) {
        int nE = min(64, end - c);
        float4 w = make_float4(0.f, 0.f, 0.f, 0.f);
        int s = 0;
        if (lane < nE) {
            s = csr_src[c + lane];
            float4 e4 = *(reinterpret_cast<const float4*>(el) + s);
            w.x = __expf(leaky(e4.x + ern.x));
            w.y = __expf(leaky(e4.y + ern.y));
            w.z = __expf(leaky(e4.z + ern.z));
            w.w = __expf(leaky(e4.w + ern.w));
        }
        denom[0] += w.x; denom[1] += w.y; denom[2] += w.z; denom[3] += w.w;
        obuf[wv][lane] = s * 256;
        *reinterpret_cast<float4*>(&wbuf[wv][lane * 4]) = w;
        __asm__ volatile("s_waitcnt lgkmcnt(0)" ::: "memory");

#pragma unroll 4
        for (int e2 = 0; e2 < nE; e2 += 2) {
            int e = e2 + g;
            float4 we = make_float4(0.f, 0.f, 0.f, 0.f);
            int off = 0;
            if (e < nE) {
                off = obuf[wv][e];
                we = *reinterpret_cast<const float4*>(&wbuf[wv][e * 4]);
            }
            ushort8v v = *reinterpret_cast<const ushort8v*>(featb + off + li * 8);
            acc[0][0] = fmaf(we.x, bf2f(v[0]), acc[0][0]);
            acc[0][1] = fmaf(we.y, bf2f(v[1]), acc[0][1]);
            acc[0][2] = fmaf(we.z, bf2f(v[2]), acc[0][2]);
            acc[0][3] = fmaf(we.w, bf2f(v[3]), acc[0][3]);
            acc[1][0] = fmaf(we.x, bf2f(v[4]), acc[1][0]);
            acc[1][1] = fmaf(we.y, bf2f(v[5]), acc[1][1]);
            acc[1][2] = fmaf(we.z, bf2f(v[6]), acc[1][2]);
            acc[1][3] = fmaf(we.w, bf2f(v[7]), acc[1][3]);
        }
        __asm__ volatile("" ::: "memory");
    }

#pragma unroll
    for (int j = 0; j < 2; ++j)
#pragma unroll
        for (int h = 0; h < 4; ++h) acc[j][h] += __shfl_xor(acc[j][h], 32);
#pragma unroll
    for (int h = 0; h < 4; ++h)
        for (int o = 32; o; o >>= 1) denom[h] += __shfl_xor(denom[h], o);

    bool has = end > begin;
#pragma unroll
    for (int hh = 0; hh < 2; ++hh) {
        int h = g * 2 + hh;
        float d0 = denom[h];
        float o0 = has ? acc[0][h] / d0 : 0.f;
        float o1 = has ? acc[1][h] / d0 : 0.f;
        int dbase = h * 64 + li * 2;
        if constexpr (RES == 1) {
            unsigned rv = *reinterpret_cast<const unsigned*>(resbuf + (size_t)node * 256 + dbase);
            o0 += bf2f((ushort)(rv & 0xffffu));
            o1 += bf2f((ushort)(rv >> 16));
        }
        float2 bv = *reinterpret_cast<const float2*>(bias + dbase);
        o0 += bv.x; o1 += bv.y;
        if constexpr (ACT) {
            o0 = o0 > 0.f ? o0 : __expf(o0) - 1.f;
            o1 = o1 > 0.f ? o1 : __expf(o1) - 1.f;
        }
        unsigned pk = (unsigned)f2bf(o0) | ((unsigned)f2bf(o1) << 16);
        *reinterpret_cast<unsigned*>(out + (size_t)node * 256 + dbase) = pk;
    }
}

// ---------------- agg H=1 (layer 2) ----------------
__global__ __launch_bounds__(256) void agg1_kernel(
    const ushort* __restrict__ featb, const float* __restrict__ el,
    const float* __restrict__ er, const int* __restrict__ row_start,
    const int* __restrict__ csr_src, const float* __restrict__ resbuf,
    const float* __restrict__ bias, float* __restrict__ out, int Nn) {
    __shared__ float wbuf[4][64];
    __shared__ int obuf[4][64];
    const int wv = threadIdx.x >> 6, lane = threadIdx.x & 63;
    const int g = lane >> 4, li = lane & 15;
    int node = blockIdx.x * 4 + wv;
    if (node >= Nn) return;

    int begin = row_start[node], end = row_start[node + 1];
    float ern = er[node];
    float denom = 0.f;
    float acc[4] = {0.f, 0.f, 0.f, 0.f};

    for (int c = begin; c < end; c += 64) {
        int nE = min(64, end - c);
        float w = 0.f;
        int s = 0;
        if (lane < nE) {
            s = csr_src[c + lane];
            w = __expf(leaky(el[s] + ern));
        }
        denom += w;
        obuf[wv][lane] = s * 64;
        wbuf[wv][lane] = w;
        __asm__ volatile("s_waitcnt lgkmcnt(0)" ::: "memory");

#pragma unroll 2
        for (int e4i = 0; e4i < nE; e4i += 4) {
            int e = e4i + g;
            float we = 0.f;
            int off = 0;
            if (e < nE) {
                off = obuf[wv][e];
                we = wbuf[wv][e];
            }
            ushort4 v = *reinterpret_cast<const ushort4*>(featb + off + li * 4);
            acc[0] = fmaf(we, bf2f(v.x), acc[0]);
            acc[1] = fmaf(we, bf2f(v.y), acc[1]);
            acc[2] = fmaf(we, bf2f(v.z), acc[2]);
            acc[3] = fmaf(we, bf2f(v.w), acc[3]);
        }
        __asm__ volatile("" ::: "memory");
    }

#pragma unroll
    for (int j = 0; j < 4; ++j) {
        acc[j] += __shfl_xor(acc[j], 16);
        acc[j] += __shfl_xor(acc[j], 32);
    }
    for (int o = 32; o; o >>= 1) denom += __shfl_xor(denom, o);

    if (g == 0) {
        bool has = end > begin;
        float4 rv = *reinterpret_cast<const float4*>(resbuf + (size_t)node * 64 + li * 4);
        float4 bv = *reinterpret_cast<const float4*>(bias + li * 4);
        float4 o4;
        o4.x = (has ? acc[0] / denom : 0.f) + rv.x + bv.x;
        o4.y = (has ? acc[1] / denom : 0.f) + rv.y + bv.y;
        o4.z = (has ? acc[2] / denom : 0.f) + rv.z + bv.z;
        o4.w = (has ? acc[3] / denom : 0.f) + rv.w + bv.w;
        *reinterpret_cast<float4*>(out + (size_t)node * 64 + li * 4) = o4;
    }
}

// ---------------- launch ----------------
extern "C" void kernel_launch(void* const* d_in, const int* in_sizes, int n_in, void* d_out,
                              int out_size, void* d_ws, size_t ws_size, hipStream_t stream) {
    const float* x   = (const float*)d_in[0];
    const int* src   = (const int*)d_in[1];
    const int* dst   = (const int*)d_in[2];
    const float* W0  = (const float*)d_in[3];
    const float* al0 = (const float*)d_in[4];
    const float* ar0 = (const float*)d_in[5];
    const float* b0  = (const float*)d_in[6];
    const float* W1  = (const float*)d_in[7];
    const float* al1 = (const float*)d_in[8];
    const float* ar1 = (const float*)d_in[9];
    const float* b1  = (const float*)d_in[10];
    const float* W2  = (const float*)d_in[11];
    const float* al2 = (const float*)d_in[12];
    const float* ar2 = (const float*)d_in[13];
    const float* b2  = (const float*)d_in[14];
    const float* Wr2 = (const float*)d_in[15];
    float* out = (float*)d_out;

    char* w = (char*)d_ws;
    size_t off = 0;
    auto alloc = [&](size_t bytes) -> char* {
        char* p = w + off;
        off += (bytes + 255) & ~(size_t)255;
        return p;
    };
    ushort* xb      = (ushort*)alloc((size_t)NNODES * 256 * 2);
    ushort* hbuf    = (ushort*)alloc((size_t)NNODES * 256 * 2);
    ushort* featb   = (ushort*)alloc((size_t)NNODES * 256 * 2);
    float* resid    = (float*)alloc((size_t)NNODES * 64 * 4);
    float* el       = (float*)alloc((size_t)NNODES * 4 * 4);
    float* er       = (float*)alloc((size_t)NNODES * 4 * 4);
    ushort* Bt0     = (ushort*)alloc(65536 * 2);
    ushort* Bt1     = (ushort*)alloc(65536 * 2);
    ushort* Bt2     = (ushort*)alloc(32768 * 2);
    int* counts     = (int*)alloc((size_t)NNODES * 4 * 2);
    int* cursor     = counts + NNODES;
    int* row_start  = (int*)alloc((size_t)(NNODES + 1) * 4);
    int* bsum       = (int*)alloc(64 * 4);
    int* csr_src    = (int*)alloc((size_t)NEDGES * 4);

    hipMemsetAsync(counts, 0, (size_t)NNODES * 4 * 2, stream);

    const int NB4 = (NNODES + 3) / 4;

    // front: hist + pack + convert (overlapped independent work)
    front_kernel<<<EBH + NPACK + NCVT, 256, 0, stream>>>(dst, counts, W0, W1, W2, Wr2,
                                                         Bt0, Bt1, Bt2, x, xb);
    scan_partial<<<NSB, 256, 0, stream>>>(counts, bsum, NNODES);
    scan_final<<<NSB, 256, 0, stream>>>(counts, bsum, row_start, NNODES, NSB);

    // layer 0 GEMM + scatter fused (scatter hides under GEMM staging)
    gemm_wide<true><<<NBM + SCB, 512, 0, stream>>>(xb, Bt0, al0, ar0, featb, el, er, NNODES,
                                                   src, dst, row_start, cursor, csr_src);
    agg4_kernel<0, true><<<NB4, 256, 0, stream>>>(featb, el, er, row_start, csr_src,
                                                  nullptr, b0, hbuf, NNODES);
    // layer 1
    gemm_wide<false><<<NBM, 512, 0, stream>>>(hbuf, Bt1, al1, ar1, featb, el, er, NNODES,
                                              nullptr, nullptr, nullptr, nullptr, nullptr);
    agg4_kernel<1, true><<<NB4, 256, 0, stream>>>(featb, el, er, row_start, csr_src,
                                                  hbuf, b1, hbuf, NNODES);
    // layer 2
    gemm_l2<<<NBM, 256, 0, stream>>>(hbuf, Bt2, al2, ar2, featb, el, er, resid, NNODES);
    agg1_kernel<<<NB4, 256, 0, stream>>>(featb, el, er, row_start, csr_src,
                                         resid, b2, out, NNODES);
}